// Round 1
// baseline (173.677 us; speedup 1.0000x reference)
//
#include <hip/hip_runtime.h>
#include <math.h>

#define HW    409600      // 640*640
#define HW4   102400      // HW/4
#define BATCH 8
#define NLAB  33
// ws layout per batch (floats): sums[33*4] @0, cnt_k[33] @132, cnt_i[33] @165, val[33] @198
#define WSF   231

__global__ void init_ws(float* ws) {
    int i = blockIdx.x * 256 + threadIdx.x;
    if (i < BATCH * WSF) ws[i] = 0.f;
}

__device__ __forceinline__ void acc1(int iv, float kv, float tv,
                                     float x0, float x1, float x2, float x3,
                                     float* bins) {
    int lab = (tv > 0.5f) ? iv : 0;
    if (lab != 0) {
        float* bb = bins + lab * 6;
        atomicAdd(bb + 5, 1.f);          // cnt_i (inst segment)
        if (kv > 0.5f) {                 // inst_k segment
            atomicAdd(bb + 0, x0);
            atomicAdd(bb + 1, x1);
            atomicAdd(bb + 2, x2);
            atomicAdd(bb + 3, x3);
            atomicAdd(bb + 4, 1.f);      // cnt_k
        }
    }
}

__global__ __launch_bounds__(256) void pass1(const float* __restrict__ emb,
                                             const int*   __restrict__ inst,
                                             const float* __restrict__ kern,
                                             const float* __restrict__ tmask,
                                             float*       __restrict__ ws) {
    __shared__ float bins[4][NLAB * 6];   // per-wave replication
    int t = threadIdx.x, b = blockIdx.y, wave = t >> 6;
    for (int i = t; i < 4 * NLAB * 6; i += 256) (&bins[0][0])[i] = 0.f;
    __syncthreads();

    const float4* emb4  = (const float4*)(emb  + (size_t)b * 4 * HW);
    const int4*   inst4 = (const int4*)  (inst + (size_t)b * HW);
    const float4* kern4 = (const float4*)(kern + (size_t)b * HW);
    const float4* tm4   = (const float4*)(tmask+ (size_t)b * HW);
    float* mb = bins[wave];

    for (int p = blockIdx.x * 256 + t; p < HW4; p += gridDim.x * 256) {
        int4   iv = inst4[p];
        float4 kv = kern4[p];
        float4 tv = tm4[p];
        float4 x0 = emb4[p];
        float4 x1 = emb4[p + HW4];
        float4 x2 = emb4[p + 2 * HW4];
        float4 x3 = emb4[p + 3 * HW4];
        acc1(iv.x, kv.x, tv.x, x0.x, x1.x, x2.x, x3.x, mb);
        acc1(iv.y, kv.y, tv.y, x0.y, x1.y, x2.y, x3.y, mb);
        acc1(iv.z, kv.z, tv.z, x0.z, x1.z, x2.z, x3.z, mb);
        acc1(iv.w, kv.w, tv.w, x0.w, x1.w, x2.w, x3.w, mb);
    }
    __syncthreads();

    float* w = ws + b * WSF;
    for (int i = t; i < NLAB * 6; i += 256) {
        float v = bins[0][i] + bins[1][i] + bins[2][i] + bins[3][i];
        if (v != 0.f) {
            int lab = i / 6, f = i % 6;
            int dst = (f < 4) ? lab * 4 + f : (f == 4 ? 132 + lab : 165 + lab);
            atomicAdd(w + dst, v);
        }
    }
}

__global__ __launch_bounds__(256) void pass2(const float* __restrict__ emb,
                                             const int*   __restrict__ inst,
                                             const float* __restrict__ tmask,
                                             float*       __restrict__ ws) {
    __shared__ float mean_s[NLAB][4];
    __shared__ float vb[4][NLAB];
    int t = threadIdx.x, b = blockIdx.y, wave = t >> 6;
    float* w = ws + b * WSF;

    if (t < NLAB) {
        float inv = 1.f / fmaxf(w[132 + t], 1.f);
        float z = (t == 0) ? 0.f : 1.f;
        mean_s[t][0] = z * w[t * 4 + 0] * inv;
        mean_s[t][1] = z * w[t * 4 + 1] * inv;
        mean_s[t][2] = z * w[t * 4 + 2] * inv;
        mean_s[t][3] = z * w[t * 4 + 3] * inv;
    }
    for (int i = t; i < 4 * NLAB; i += 256) (&vb[0][0])[i] = 0.f;
    __syncthreads();

    const float4* emb4  = (const float4*)(emb  + (size_t)b * 4 * HW);
    const int4*   inst4 = (const int4*)  (inst + (size_t)b * HW);
    const float4* tm4   = (const float4*)(tmask+ (size_t)b * HW);
    float* mv = vb[wave];

    for (int p = blockIdx.x * 256 + t; p < HW4; p += gridDim.x * 256) {
        int4   iv = inst4[p];
        float4 tv = tm4[p];
        float4 x0 = emb4[p];
        float4 x1 = emb4[p + HW4];
        float4 x2 = emb4[p + 2 * HW4];
        float4 x3 = emb4[p + 3 * HW4];
        #pragma unroll
        for (int e = 0; e < 4; ++e) {
            int   ivv = (e == 0) ? iv.x : (e == 1) ? iv.y : (e == 2) ? iv.z : iv.w;
            float tvv = (e == 0) ? tv.x : (e == 1) ? tv.y : (e == 2) ? tv.z : tv.w;
            float a0  = (e == 0) ? x0.x : (e == 1) ? x0.y : (e == 2) ? x0.z : x0.w;
            float a1  = (e == 0) ? x1.x : (e == 1) ? x1.y : (e == 2) ? x1.z : x1.w;
            float a2  = (e == 0) ? x2.x : (e == 1) ? x2.y : (e == 2) ? x2.z : x2.w;
            float a3  = (e == 0) ? x3.x : (e == 1) ? x3.y : (e == 2) ? x3.z : x3.w;
            int lab = (tvv > 0.5f) ? ivv : 0;
            if (lab != 0) {
                float d0 = a0 - mean_s[lab][0];
                float d1 = a1 - mean_s[lab][1];
                float d2 = a2 - mean_s[lab][2];
                float d3 = a3 - mean_s[lab][3];
                float dist = sqrtf(d0 * d0 + d1 * d1 + d2 * d2 + d3 * d3);
                float u = fmaxf(dist - 0.5f, 0.f);
                atomicAdd(mv + lab, logf(u * u + 1.f));
            }
        }
    }
    __syncthreads();
    for (int i = t; i < NLAB; i += 256) {
        float v = vb[0][i] + vb[1][i] + vb[2][i] + vb[3][i];
        if (v != 0.f) atomicAdd(w + 198 + i, v);
    }
}

__global__ __launch_bounds__(256) void final_kernel(const float* __restrict__ ws,
                                                    float* __restrict__ out) {
    __shared__ float mean_s[NLAB][4];
    __shared__ float red[256];
    int t = threadIdx.x;
    float total = 0.f;
    for (int b = 0; b < BATCH; ++b) {
        const float* w = ws + b * WSF;
        if (t < NLAB) {
            float inv = 1.f / fmaxf(w[132 + t], 1.f);
            float z = (t == 0) ? 0.f : 1.f;
            mean_s[t][0] = z * w[t * 4 + 0] * inv;
            mean_s[t][1] = z * w[t * 4 + 1] * inv;
            mean_s[t][2] = z * w[t * 4 + 2] * inv;
            mean_s[t][3] = z * w[t * 4 + 3] * inv;
        }
        __syncthreads();
        // l_agg partial: labels 1..32
        float part = 0.f;
        if (t >= 1 && t < NLAB) {
            float ci = fmaxf(w[165 + t], 1.f);
            part = (w[198 + t] / ci) * (1.f / 32.f);
        }
        // l_dis partial over 32x32 pairs (labels 1..32)
        float disp = 0.f;
        for (int p = t; p < 1024; p += 256) {
            int i = p >> 5, j = p & 31;
            if (i != j) {
                float d0 = mean_s[i + 1][0] - mean_s[j + 1][0];
                float d1 = mean_s[i + 1][1] - mean_s[j + 1][1];
                float d2 = mean_s[i + 1][2] - mean_s[j + 1][2];
                float d3 = mean_s[i + 1][3] - mean_s[j + 1][3];
                float pd = sqrtf(d0 * d0 + d1 * d1 + d2 * d2 + d3 * d3);
                float u = fmaxf(2.0f * 1.5f - pd, 0.f);
                disp += logf(u * u + 1.f);
            }
        }
        disp *= 1.f / (32.f * 31.f);
        // l_reg partial
        float regp = 0.f;
        if (t >= 1 && t < NLAB) {
            float n2 = mean_s[t][0] * mean_s[t][0] + mean_s[t][1] * mean_s[t][1] +
                       mean_s[t][2] * mean_s[t][2] + mean_s[t][3] * mean_s[t][3];
            regp = logf(sqrtf(n2) + 1.f) * (0.001f / 33.f);
        }
        red[t] = part + disp + regp;
        __syncthreads();
        for (int s = 128; s > 0; s >>= 1) {
            if (t < s) red[t] += red[t + s];
            __syncthreads();
        }
        if (t == 0) total += red[0];
        __syncthreads();
    }
    if (t == 0) out[0] = total * (1.f / BATCH);
}

extern "C" void kernel_launch(void* const* d_in, const int* in_sizes, int n_in,
                              void* d_out, int out_size, void* d_ws, size_t ws_size,
                              hipStream_t stream) {
    const float* emb   = (const float*)d_in[0];
    const int*   inst  = (const int*)  d_in[1];
    const float* kern  = (const float*)d_in[2];
    const float* tmask = (const float*)d_in[3];
    float* ws  = (float*)d_ws;
    float* out = (float*)d_out;

    init_ws<<<dim3((BATCH * WSF + 255) / 256), 256, 0, stream>>>(ws);
    dim3 grid(128, BATCH);
    pass1<<<grid, 256, 0, stream>>>(emb, inst, kern, tmask, ws);
    pass2<<<grid, 256, 0, stream>>>(emb, inst, tmask, ws);
    final_kernel<<<1, 256, 0, stream>>>(ws, out);
}